// Round 4
// baseline (1125.160 us; speedup 1.0000x reference)
//
#include <hip/hip_runtime.h>
#include <hip/hip_bf16.h>

#define NTH     512
#define NSTEPS  100
#define PITERS  50
#define LAMBDAV 0.1f

typedef __bf16 bf16x8 __attribute__((ext_vector_type(8)));
typedef float  f32x4  __attribute__((ext_vector_type(4)));

__device__ __forceinline__ unsigned short f2bf(float x) {
    unsigned int u = __builtin_bit_cast(unsigned int, x);
    unsigned int r = (u + 0x7FFFu + ((u >> 16) & 1u)) >> 16;   // RNE
    return (unsigned short)r;
}
__device__ __forceinline__ float bf2f(unsigned short h) {
    unsigned int u = ((unsigned int)h) << 16;
    return __builtin_bit_cast(float, u);
}

// LDS map — audited, non-overlapping, 147456 B total:
//   yF  fp32 [64][256]        @0       (65536 B)  stride 1024  (wst overlay during init)
//   wtl bf16 W-lo^T [64][256] @65536   (32768 B)  stride 512   (phase-1 B-lo)
//   whb bf16 W-hi  [256][64]  @98304   (32768 B)  stride 128   (phase-2 B-hi)
//   rhb bf16 R-hi  [64][64]   @131072  (8192 B)   stride 128
//   rlb bf16 R-lo  [64][64]   @139264  (8192 B)   stride 128
// phase-2 W-lo lives in registers (8 frags/wave). All hot accesses XOR-swizzled
// on 16B chunks by ((row&7)<<4).

__global__ __launch_bounds__(NTH, 2)
void fista4(const float* __restrict__ inp, const float* __restrict__ Wg,
            const float* __restrict__ X0, float* __restrict__ out)
{
    __shared__ __align__(16) char lds[147456];
    __shared__ __align__(16) float vf[256];
    __shared__ __align__(16) float up[256];
    __shared__ __align__(16) float uf[64];
    __shared__ float red[16];
    __shared__ float scal[2];

    char* const yF  = lds;
    char* const wtl = lds + 65536;
    char* const whb = lds + 98304;
    char* const rhb = lds + 131072;
    char* const rlb = lds + 139264;
    char* const wst = lds;            // fp32 W staging overlay on yF

    const int tid  = threadIdx.x;
    const int w    = tid >> 6;
    const int lane = tid & 63;
    const int l4   = lane >> 4;
    const int ln   = lane & 15;
    const int rb   = blockIdx.x * 64;

    const int mi = w >> 1, nh = w & 1;   // phase-1: m-tile mi, n-tiles {2nh, 2nh+1}
    const int mp = w >> 2, nq = w & 3;   // phase-2: m-tiles {2mp,2mp+1}, n-tiles {4nq..4nq+3}

    // ---- stage W fp32 (swizzled) ----
    #pragma unroll
    for (int i = 0; i < 8; ++i) {
        int wi = (tid + i * NTH) * 4; int j = wi >> 6, k = wi & 63;
        f32x4 v = *(const f32x4*)&Wg[wi];
        *(f32x4*)(wst + j * 256 + ((k * 4) ^ ((j & 7) << 4))) = v;
    }
    // ---- bf16 planes: W-hi row-major + W-lo transposed ----
    for (int i = tid; i < 256 * 64; i += NTH) {
        int j = i >> 6, k = i & 63;
        float wv = Wg[i];
        unsigned short h = f2bf(wv);
        unsigned short l = f2bf(wv - bf2f(h));
        *(unsigned short*)(whb + j * 128 + ((k * 2) ^ ((j & 7) << 4))) = h;
        *(unsigned short*)(wtl + k * 512 + ((j * 2) ^ ((k & 7) << 4))) = l;
    }

    // ---- per-thread constants ----
    float nin[2][4];
    #pragma unroll
    for (int q = 0; q < 2; ++q)
        #pragma unroll
        for (int r = 0; r < 4; ++r)
            nin[q][r] = -inp[(size_t)(rb + mi * 16 + 4 * l4 + r) * 64 + (2 * nh + q) * 16 + ln];

    float xm[2][4][4], ym[2][4][4];
    #pragma unroll
    for (int s = 0; s < 2; ++s)
      #pragma unroll
      for (int q = 0; q < 4; ++q)
        #pragma unroll
        for (int r = 0; r < 4; ++r) {
            float v = X0[(size_t)(rb + (2 * mp + s) * 16 + 4 * l4 + r) * 256 + (4 * nq + q) * 16 + ln];
            xm[s][q][r] = v; ym[s][q][r] = v;
        }

    if (tid < 256) vf[tid] = 0.0625f;
    __syncthreads();

    // ---- Lipschitz: 50 power iterations of Q = 2 W W^T (R2-verified) ----
    for (int it = 0; it <= PITERS; ++it) {
        if (tid < 256) {
            int col = tid & 63, jq = tid >> 6;
            float s = 0.f;
            #pragma unroll 4
            for (int j = jq * 64; j < jq * 64 + 64; ++j)
                s += vf[j] * *(const float*)(wst + j * 256 + ((col * 4) ^ ((j & 7) << 4)));
            up[tid] = s;
        }
        __syncthreads();
        if (tid < 64) uf[tid] = up[tid] + up[tid + 64] + up[tid + 128] + up[tid + 192];
        __syncthreads();
        float w2 = 0.f;
        if (tid < 256) {
            float s = 0.f;
            #pragma unroll
            for (int kc = 0; kc < 64; kc += 4) {
                f32x4 wv = *(const f32x4*)(wst + tid * 256 + ((kc * 4) ^ ((tid & 7) << 4)));
                f32x4 u4 = *(const f32x4*)&uf[kc];
                s += wv.x * u4.x + wv.y * u4.y + wv.z * u4.z + wv.w * u4.w;
            }
            w2 = 2.f * s;
        }
        float sq = (tid < 256) ? ((it == PITERS) ? vf[tid] * w2 : w2 * w2) : 0.f;
        #pragma unroll
        for (int off = 32; off >= 1; off >>= 1) sq += __shfl_down(sq, off);
        if (tid < 256 && lane == 0) red[tid >> 6] = sq;
        __syncthreads();
        float tot = red[0] + red[1] + red[2] + red[3];
        if (it < PITERS) { if (tid < 256) vf[tid] = w2 * (1.f / sqrtf(tot)); }
        else if (tid == 0) { scal[0] = 1.f / tot; scal[1] = LAMBDAV / tot; }
        __syncthreads();
    }
    const float c2  = 2.f * scal[0];
    const float thr = scal[1];

    // ---- phase-1 W-hi fragments -> registers (16 frags = 64 VGPR) ----
    bf16x8 wbh[2][8];
    #pragma unroll
    for (int q = 0; q < 2; ++q) {
        const int col4 = ((2 * nh + q) * 16 + ln) * 4;
        #pragma unroll
        for (int c = 0; c < 8; ++c) {
            union { unsigned short u[8]; bf16x8 v; } p;
            #pragma unroll
            for (int t = 0; t < 8; ++t) {
                int j = c * 32 + 8 * l4 + t;
                p.u[t] = f2bf(*(const float*)(wst + j * 256 + (col4 ^ ((j & 7) << 4))));
            }
            wbh[q][c] = p.v;
        }
    }
    // ---- phase-2 W-lo fragments -> registers (8 frags = 32 VGPR) ----
    bf16x8 w2lo[4][2];
    #pragma unroll
    for (int q = 0; q < 4; ++q) {
        const int brow = (4 * nq + q) * 16 + ln;
        #pragma unroll
        for (int c = 0; c < 2; ++c) {
            union { unsigned short u[8]; bf16x8 v; } p;
            #pragma unroll
            for (int t = 0; t < 8; ++t) {
                int k = c * 32 + 8 * l4 + t;
                float wv = *(const float*)(wst + brow * 256 + ((k * 4) ^ ((brow & 7) << 4)));
                p.u[t] = f2bf(wv - bf2f(f2bf(wv)));
            }
            w2lo[q][c] = p.v;
        }
    }
    __syncthreads();   // all wst consumers done; yF region free

    // ---- y0 = X0 into fp32 LDS ----
    #pragma unroll
    for (int s = 0; s < 2; ++s)
      #pragma unroll
      for (int q = 0; q < 4; ++q)
        #pragma unroll
        for (int r = 0; r < 4; ++r) {
            int row = (2 * mp + s) * 16 + 4 * l4 + r;
            int col = (4 * nq + q) * 16 + ln;
            *(float*)(yF + row * 1024 + ((col * 4) ^ ((row & 7) << 4))) = ym[s][q][r];
        }
    __syncthreads();

    const int arow = mi * 16 + ln;
    const int ax   = (arow & 7) << 4;
    const int b0   = (2 * nh) * 16 + ln;
    const int b1   = b0 + 16;
    const int bx   = (ln & 7) << 4;           // b0&7 == b1&7 == ln&7

    float tt = 1.f;
    for (int step = 0; step < NSTEPS; ++step) {
        // ======== phase 1: R = y W - in ========
        f32x4 a0 = { nin[0][0], nin[0][1], nin[0][2], nin[0][3] };
        f32x4 a1 = { nin[1][0], nin[1][1], nin[1][2], nin[1][3] };
        #pragma unroll
        for (int c = 0; c < 8; ++c) {
            const int lb = c * 128 + l4 * 32;
            f32x4 v0 = *(const f32x4*)(yF + arow * 1024 + (lb ^ ax));
            f32x4 v1 = *(const f32x4*)(yF + arow * 1024 + ((lb + 16) ^ ax));
            union { unsigned short u[8]; bf16x8 v; } ah, al;
            #pragma unroll
            for (int t = 0; t < 4; ++t) {
                float f = v0[t]; unsigned short h = f2bf(f);
                ah.u[t] = h; al.u[t] = f2bf(f - bf2f(h));
            }
            #pragma unroll
            for (int t = 0; t < 4; ++t) {
                float f = v1[t]; unsigned short h = f2bf(f);
                ah.u[4 + t] = h; al.u[4 + t] = f2bf(f - bf2f(h));
            }
            const int kb = c * 64 + l4 * 16;
            bf16x8 bl0 = *(const bf16x8*)(wtl + b0 * 512 + (kb ^ bx));
            bf16x8 bl1 = *(const bf16x8*)(wtl + b1 * 512 + (kb ^ bx));
            a0 = __builtin_amdgcn_mfma_f32_16x16x32_bf16(ah.v, wbh[0][c], a0, 0, 0, 0);
            a0 = __builtin_amdgcn_mfma_f32_16x16x32_bf16(al.v, wbh[0][c], a0, 0, 0, 0);
            a0 = __builtin_amdgcn_mfma_f32_16x16x32_bf16(ah.v, bl0,       a0, 0, 0, 0);
            a1 = __builtin_amdgcn_mfma_f32_16x16x32_bf16(ah.v, wbh[1][c], a1, 0, 0, 0);
            a1 = __builtin_amdgcn_mfma_f32_16x16x32_bf16(al.v, wbh[1][c], a1, 0, 0, 0);
            a1 = __builtin_amdgcn_mfma_f32_16x16x32_bf16(ah.v, bl1,       a1, 0, 0, 0);
        }
        #pragma unroll
        for (int q = 0; q < 2; ++q)
            #pragma unroll
            for (int r = 0; r < 4; ++r) {
                int row = mi * 16 + 4 * l4 + r;
                int off = row * 128 + ((((2 * nh + q) * 16 + ln) * 2) ^ ((row & 7) << 4));
                float v = q ? a1[r] : a0[r];
                unsigned short h = f2bf(v);
                *(unsigned short*)(rhb + off) = h;
                *(unsigned short*)(rlb + off) = f2bf(v - bf2f(h));
            }
        __syncthreads();

        // ======== phase 2: g = R W^T ========
        f32x4 g2[2][4];
        #pragma unroll
        for (int s = 0; s < 2; ++s)
            #pragma unroll
            for (int q = 0; q < 4; ++q) g2[s][q] = (f32x4){0.f, 0.f, 0.f, 0.f};
        #pragma unroll
        for (int c = 0; c < 2; ++c) {
            const int kb = c * 64 + l4 * 16;
            const int r0 = (2 * mp) * 16 + ln;
            const int r1 = r0 + 16;
            const int rx = (ln & 7) << 4;
            bf16x8 rh0 = *(const bf16x8*)(rhb + r0 * 128 + (kb ^ rx));
            bf16x8 rl0 = *(const bf16x8*)(rlb + r0 * 128 + (kb ^ rx));
            bf16x8 rh1 = *(const bf16x8*)(rhb + r1 * 128 + (kb ^ rx));
            bf16x8 rl1 = *(const bf16x8*)(rlb + r1 * 128 + (kb ^ rx));
            #pragma unroll
            for (int q = 0; q < 4; ++q) {
                const int brow = (4 * nq + q) * 16 + ln;
                bf16x8 bh = *(const bf16x8*)(whb + brow * 128 + (kb ^ rx));
                g2[0][q] = __builtin_amdgcn_mfma_f32_16x16x32_bf16(rh0, bh,        g2[0][q], 0, 0, 0);
                g2[0][q] = __builtin_amdgcn_mfma_f32_16x16x32_bf16(rl0, bh,        g2[0][q], 0, 0, 0);
                g2[0][q] = __builtin_amdgcn_mfma_f32_16x16x32_bf16(rh0, w2lo[q][c], g2[0][q], 0, 0, 0);
                g2[1][q] = __builtin_amdgcn_mfma_f32_16x16x32_bf16(rh1, bh,        g2[1][q], 0, 0, 0);
                g2[1][q] = __builtin_amdgcn_mfma_f32_16x16x32_bf16(rl1, bh,        g2[1][q], 0, 0, 0);
                g2[1][q] = __builtin_amdgcn_mfma_f32_16x16x32_bf16(rh1, w2lo[q][c], g2[1][q], 0, 0, 0);
            }
        }

        // ======== update: prox + momentum, write y (fp32) ========
        const float t2v = 0.5f + 0.5f * sqrtf(1.f + 4.f * tt * tt);
        const float mom = (tt - 1.f) / t2v;
        tt = t2v;
        #pragma unroll
        for (int s = 0; s < 2; ++s)
          #pragma unroll
          for (int q = 0; q < 4; ++q)
            #pragma unroll
            for (int r = 0; r < 4; ++r) {
                float u  = ym[s][q][r] - c2 * g2[s][q][r];
                float x2 = fmaxf(u - thr, 0.f) + fminf(u + thr, 0.f);
                float yn = x2 + mom * (x2 - xm[s][q][r]);
                xm[s][q][r] = x2; ym[s][q][r] = yn;
                int row = (2 * mp + s) * 16 + 4 * l4 + r;
                int col = (4 * nq + q) * 16 + ln;
                *(float*)(yF + row * 1024 + ((col * 4) ^ ((row & 7) << 4))) = yn;
            }
        __syncthreads();
    }

    // ---- store X ----
    #pragma unroll
    for (int s = 0; s < 2; ++s)
      #pragma unroll
      for (int q = 0; q < 4; ++q)
        #pragma unroll
        for (int r = 0; r < 4; ++r)
            out[(size_t)(rb + (2 * mp + s) * 16 + 4 * l4 + r) * 256 + (4 * nq + q) * 16 + ln] = xm[s][q][r];
}

extern "C" void kernel_launch(void* const* d_in, const int* in_sizes, int n_in,
                              void* d_out, int out_size, void* d_ws, size_t ws_size,
                              hipStream_t stream) {
    (void)in_sizes; (void)n_in; (void)d_ws; (void)ws_size; (void)out_size;
    const float* inp = (const float*)d_in[0];   // [16384, 64]
    const float* Wg  = (const float*)d_in[1];   // [256, 64]
    const float* X0  = (const float*)d_in[2];   // [16384, 256]
    float* outp      = (float*)d_out;           // [16384, 256]
    fista4<<<16384 / 64, NTH, 0, stream>>>(inp, Wg, X0, outp);
}

// Round 5
// 1120.135 us; speedup vs baseline: 1.0045x; 1.0045x over previous
//
#include <hip/hip_runtime.h>
#include <hip/hip_bf16.h>

#define NTH     512
#define NSTEPS  100
#define PITERS  50
#define LAMBDAV 0.1f

typedef __bf16 bf16x8 __attribute__((ext_vector_type(8)));
typedef float  f32x4  __attribute__((ext_vector_type(4)));

__device__ __forceinline__ unsigned short f2bf(float x) {
    unsigned int u = __builtin_bit_cast(unsigned int, x);
    unsigned int r = (u + 0x7FFFu + ((u >> 16) & 1u)) >> 16;   // RNE
    return (unsigned short)r;
}
__device__ __forceinline__ float bf2f(unsigned short h) {
    unsigned int u = ((unsigned int)h) << 16;
    return __builtin_bit_cast(float, u);
}

// LDS map — audited, non-overlapping, 147456 B total:
//   yF  fp32 [64][256]        @0       (65536 B)  stride 1024  (wst overlay during init)
//   wtl bf16 W-lo^T [64][256] @65536   (32768 B)  stride 512   (phase-1 B-lo)
//   whb bf16 W-hi  [256][64]  @98304   (32768 B)  stride 128   (phase-2 B-hi)
//   rhb bf16 R-hi  [64][64]   @131072  (8192 B)   stride 128
//   rlb bf16 R-lo  [64][64]   @139264  (8192 B)   stride 128
// phase-2 W-lo in registers. All hot accesses XOR-swizzled by ((row&7)<<4).
// waves_per_eu pinned to (2,2): LDS already caps at 1 block/CU (= 2 waves/EU),
// so the allocator must use the full 256-VGPR budget instead of spilling.

__global__ __launch_bounds__(NTH) __attribute__((amdgpu_waves_per_eu(2, 2)))
void fista5(const float* __restrict__ inp, const float* __restrict__ Wg,
            const float* __restrict__ X0, float* __restrict__ out)
{
    __shared__ __align__(16) char lds[147456];
    __shared__ __align__(16) float vf[256];
    __shared__ __align__(16) float up[256];
    __shared__ __align__(16) float uf[64];
    __shared__ float red[16];
    __shared__ float scal[2];

    char* const yF  = lds;
    char* const wtl = lds + 65536;
    char* const whb = lds + 98304;
    char* const rhb = lds + 131072;
    char* const rlb = lds + 139264;
    char* const wst = lds;            // fp32 W staging overlay on yF

    const int tid  = threadIdx.x;
    const int w    = tid >> 6;
    const int lane = tid & 63;
    const int l4   = lane >> 4;
    const int ln   = lane & 15;
    const int rb   = blockIdx.x * 64;

    const int mi = w >> 1, nh = w & 1;   // phase-1: m-tile mi, n-tiles {2nh, 2nh+1}
    const int mp = w >> 2, nq = w & 3;   // phase-2: m-tiles {2mp,2mp+1}, n-tiles {4nq..4nq+3}

    // ---- stage W fp32 (swizzled) ----
    #pragma unroll
    for (int i = 0; i < 8; ++i) {
        int wi = (tid + i * NTH) * 4; int j = wi >> 6, k = wi & 63;
        f32x4 v = *(const f32x4*)&Wg[wi];
        *(f32x4*)(wst + j * 256 + ((k * 4) ^ ((j & 7) << 4))) = v;
    }
    // ---- bf16 planes: W-hi row-major + W-lo transposed ----
    for (int i = tid; i < 256 * 64; i += NTH) {
        int j = i >> 6, k = i & 63;
        float wv = Wg[i];
        unsigned short h = f2bf(wv);
        unsigned short l = f2bf(wv - bf2f(h));
        *(unsigned short*)(whb + j * 128 + ((k * 2) ^ ((j & 7) << 4))) = h;
        *(unsigned short*)(wtl + k * 512 + ((j * 2) ^ ((k & 7) << 4))) = l;
    }

    // ---- per-thread constants ----
    float nin[2][4];
    #pragma unroll
    for (int q = 0; q < 2; ++q)
        #pragma unroll
        for (int r = 0; r < 4; ++r)
            nin[q][r] = -inp[(size_t)(rb + mi * 16 + 4 * l4 + r) * 64 + (2 * nh + q) * 16 + ln];

    float xm[2][4][4], ym[2][4][4];
    #pragma unroll
    for (int s = 0; s < 2; ++s)
      #pragma unroll
      for (int q = 0; q < 4; ++q)
        #pragma unroll
        for (int r = 0; r < 4; ++r) {
            float v = X0[(size_t)(rb + (2 * mp + s) * 16 + 4 * l4 + r) * 256 + (4 * nq + q) * 16 + ln];
            xm[s][q][r] = v; ym[s][q][r] = v;
        }

    if (tid < 256) vf[tid] = 0.0625f;
    __syncthreads();

    // ---- Lipschitz: 50 power iterations of Q = 2 W W^T (R2-verified) ----
    for (int it = 0; it <= PITERS; ++it) {
        if (tid < 256) {
            int col = tid & 63, jq = tid >> 6;
            float s = 0.f;
            #pragma unroll 4
            for (int j = jq * 64; j < jq * 64 + 64; ++j)
                s += vf[j] * *(const float*)(wst + j * 256 + ((col * 4) ^ ((j & 7) << 4)));
            up[tid] = s;
        }
        __syncthreads();
        if (tid < 64) uf[tid] = up[tid] + up[tid + 64] + up[tid + 128] + up[tid + 192];
        __syncthreads();
        float w2 = 0.f;
        if (tid < 256) {
            float s = 0.f;
            #pragma unroll
            for (int kc = 0; kc < 64; kc += 4) {
                f32x4 wv = *(const f32x4*)(wst + tid * 256 + ((kc * 4) ^ ((tid & 7) << 4)));
                f32x4 u4 = *(const f32x4*)&uf[kc];
                s += wv.x * u4.x + wv.y * u4.y + wv.z * u4.z + wv.w * u4.w;
            }
            w2 = 2.f * s;
        }
        float sq = (tid < 256) ? ((it == PITERS) ? vf[tid] * w2 : w2 * w2) : 0.f;
        #pragma unroll
        for (int off = 32; off >= 1; off >>= 1) sq += __shfl_down(sq, off);
        if (tid < 256 && lane == 0) red[tid >> 6] = sq;
        __syncthreads();
        float tot = red[0] + red[1] + red[2] + red[3];
        if (it < PITERS) { if (tid < 256) vf[tid] = w2 * (1.f / sqrtf(tot)); }
        else if (tid == 0) { scal[0] = 1.f / tot; scal[1] = LAMBDAV / tot; }
        __syncthreads();
    }
    const float c2  = 2.f * scal[0];
    const float thr = scal[1];

    // ---- phase-1 W-hi fragments -> registers (16 frags = 64 VGPR) ----
    bf16x8 wbh[2][8];
    #pragma unroll
    for (int q = 0; q < 2; ++q) {
        const int col4 = ((2 * nh + q) * 16 + ln) * 4;
        #pragma unroll
        for (int c = 0; c < 8; ++c) {
            union { unsigned short u[8]; bf16x8 v; } p;
            #pragma unroll
            for (int t = 0; t < 8; ++t) {
                int j = c * 32 + 8 * l4 + t;
                p.u[t] = f2bf(*(const float*)(wst + j * 256 + (col4 ^ ((j & 7) << 4))));
            }
            wbh[q][c] = p.v;
        }
    }
    // ---- phase-2 W-lo fragments -> registers (8 frags = 32 VGPR) ----
    bf16x8 w2lo[4][2];
    #pragma unroll
    for (int q = 0; q < 4; ++q) {
        const int brow = (4 * nq + q) * 16 + ln;
        #pragma unroll
        for (int c = 0; c < 2; ++c) {
            union { unsigned short u[8]; bf16x8 v; } p;
            #pragma unroll
            for (int t = 0; t < 8; ++t) {
                int k = c * 32 + 8 * l4 + t;
                float wv = *(const float*)(wst + brow * 256 + ((k * 4) ^ ((brow & 7) << 4)));
                p.u[t] = f2bf(wv - bf2f(f2bf(wv)));
            }
            w2lo[q][c] = p.v;
        }
    }
    __syncthreads();   // all wst consumers done; yF region free

    // ---- y0 = X0 into fp32 LDS ----
    #pragma unroll
    for (int s = 0; s < 2; ++s)
      #pragma unroll
      for (int q = 0; q < 4; ++q)
        #pragma unroll
        for (int r = 0; r < 4; ++r) {
            int row = (2 * mp + s) * 16 + 4 * l4 + r;
            int col = (4 * nq + q) * 16 + ln;
            *(float*)(yF + row * 1024 + ((col * 4) ^ ((row & 7) << 4))) = ym[s][q][r];
        }
    __syncthreads();

    const int arow = mi * 16 + ln;
    const int ax   = (arow & 7) << 4;
    const int b0   = (2 * nh) * 16 + ln;
    const int b1   = b0 + 16;
    const int bx   = (ln & 7) << 4;           // b0&7 == b1&7 == ln&7

    float tt = 1.f;
    for (int step = 0; step < NSTEPS; ++step) {
        // ======== phase 1: R = y W - in ========
        f32x4 a0 = { nin[0][0], nin[0][1], nin[0][2], nin[0][3] };
        f32x4 a1 = { nin[1][0], nin[1][1], nin[1][2], nin[1][3] };
        #pragma unroll
        for (int c = 0; c < 8; ++c) {
            const int lb = c * 128 + l4 * 32;
            f32x4 v0 = *(const f32x4*)(yF + arow * 1024 + (lb ^ ax));
            f32x4 v1 = *(const f32x4*)(yF + arow * 1024 + ((lb + 16) ^ ax));
            union { unsigned short u[8]; bf16x8 v; } ah, al;
            #pragma unroll
            for (int t = 0; t < 4; ++t) {
                float f = v0[t]; unsigned short h = f2bf(f);
                ah.u[t] = h; al.u[t] = f2bf(f - bf2f(h));
            }
            #pragma unroll
            for (int t = 0; t < 4; ++t) {
                float f = v1[t]; unsigned short h = f2bf(f);
                ah.u[4 + t] = h; al.u[4 + t] = f2bf(f - bf2f(h));
            }
            const int kb = c * 64 + l4 * 16;
            bf16x8 bl0 = *(const bf16x8*)(wtl + b0 * 512 + (kb ^ bx));
            bf16x8 bl1 = *(const bf16x8*)(wtl + b1 * 512 + (kb ^ bx));
            a0 = __builtin_amdgcn_mfma_f32_16x16x32_bf16(ah.v, wbh[0][c], a0, 0, 0, 0);
            a0 = __builtin_amdgcn_mfma_f32_16x16x32_bf16(al.v, wbh[0][c], a0, 0, 0, 0);
            a0 = __builtin_amdgcn_mfma_f32_16x16x32_bf16(ah.v, bl0,       a0, 0, 0, 0);
            a1 = __builtin_amdgcn_mfma_f32_16x16x32_bf16(ah.v, wbh[1][c], a1, 0, 0, 0);
            a1 = __builtin_amdgcn_mfma_f32_16x16x32_bf16(al.v, wbh[1][c], a1, 0, 0, 0);
            a1 = __builtin_amdgcn_mfma_f32_16x16x32_bf16(ah.v, bl1,       a1, 0, 0, 0);
        }
        #pragma unroll
        for (int q = 0; q < 2; ++q)
            #pragma unroll
            for (int r = 0; r < 4; ++r) {
                int row = mi * 16 + 4 * l4 + r;
                int off = row * 128 + ((((2 * nh + q) * 16 + ln) * 2) ^ ((row & 7) << 4));
                float v = q ? a1[r] : a0[r];
                unsigned short h = f2bf(v);
                *(unsigned short*)(rhb + off) = h;
                *(unsigned short*)(rlb + off) = f2bf(v - bf2f(h));
            }
        __syncthreads();

        // ======== phase 2: g = R W^T ========
        f32x4 g2[2][4];
        #pragma unroll
        for (int s = 0; s < 2; ++s)
            #pragma unroll
            for (int q = 0; q < 4; ++q) g2[s][q] = (f32x4){0.f, 0.f, 0.f, 0.f};
        #pragma unroll
        for (int c = 0; c < 2; ++c) {
            const int kb = c * 64 + l4 * 16;
            const int r0 = (2 * mp) * 16 + ln;
            const int r1 = r0 + 16;
            const int rx = (ln & 7) << 4;
            bf16x8 rh0 = *(const bf16x8*)(rhb + r0 * 128 + (kb ^ rx));
            bf16x8 rl0 = *(const bf16x8*)(rlb + r0 * 128 + (kb ^ rx));
            bf16x8 rh1 = *(const bf16x8*)(rhb + r1 * 128 + (kb ^ rx));
            bf16x8 rl1 = *(const bf16x8*)(rlb + r1 * 128 + (kb ^ rx));
            #pragma unroll
            for (int q = 0; q < 4; ++q) {
                const int brow = (4 * nq + q) * 16 + ln;
                bf16x8 bh = *(const bf16x8*)(whb + brow * 128 + (kb ^ rx));
                g2[0][q] = __builtin_amdgcn_mfma_f32_16x16x32_bf16(rh0, bh,         g2[0][q], 0, 0, 0);
                g2[0][q] = __builtin_amdgcn_mfma_f32_16x16x32_bf16(rl0, bh,         g2[0][q], 0, 0, 0);
                g2[0][q] = __builtin_amdgcn_mfma_f32_16x16x32_bf16(rh0, w2lo[q][c], g2[0][q], 0, 0, 0);
                g2[1][q] = __builtin_amdgcn_mfma_f32_16x16x32_bf16(rh1, bh,         g2[1][q], 0, 0, 0);
                g2[1][q] = __builtin_amdgcn_mfma_f32_16x16x32_bf16(rl1, bh,         g2[1][q], 0, 0, 0);
                g2[1][q] = __builtin_amdgcn_mfma_f32_16x16x32_bf16(rh1, w2lo[q][c], g2[1][q], 0, 0, 0);
            }
        }

        // ======== update: prox + momentum, write y (fp32) ========
        const float t2v = 0.5f + 0.5f * sqrtf(1.f + 4.f * tt * tt);
        const float mom = (tt - 1.f) / t2v;
        tt = t2v;
        #pragma unroll
        for (int s = 0; s < 2; ++s)
          #pragma unroll
          for (int q = 0; q < 4; ++q)
            #pragma unroll
            for (int r = 0; r < 4; ++r) {
                float u  = ym[s][q][r] - c2 * g2[s][q][r];
                float x2 = fmaxf(u - thr, 0.f) + fminf(u + thr, 0.f);
                float yn = x2 + mom * (x2 - xm[s][q][r]);
                xm[s][q][r] = x2; ym[s][q][r] = yn;
                int row = (2 * mp + s) * 16 + 4 * l4 + r;
                int col = (4 * nq + q) * 16 + ln;
                *(float*)(yF + row * 1024 + ((col * 4) ^ ((row & 7) << 4))) = yn;
            }
        __syncthreads();
    }

    // ---- store X ----
    #pragma unroll
    for (int s = 0; s < 2; ++s)
      #pragma unroll
      for (int q = 0; q < 4; ++q)
        #pragma unroll
        for (int r = 0; r < 4; ++r)
            out[(size_t)(rb + (2 * mp + s) * 16 + 4 * l4 + r) * 256 + (4 * nq + q) * 16 + ln] = xm[s][q][r];
}

extern "C" void kernel_launch(void* const* d_in, const int* in_sizes, int n_in,
                              void* d_out, int out_size, void* d_ws, size_t ws_size,
                              hipStream_t stream) {
    (void)in_sizes; (void)n_in; (void)d_ws; (void)ws_size; (void)out_size;
    const float* inp = (const float*)d_in[0];   // [16384, 64]
    const float* Wg  = (const float*)d_in[1];   // [256, 64]
    const float* X0  = (const float*)d_in[2];   // [16384, 256]
    float* outp      = (float*)d_out;           // [16384, 256]
    fista5<<<16384 / 64, NTH, 0, stream>>>(inp, Wg, X0, outp);
}

// Round 6
// 1066.961 us; speedup vs baseline: 1.0545x; 1.0498x over previous
//
#include <hip/hip_runtime.h>
#include <hip/hip_bf16.h>

#define NTH     512
#define NSTEPS  100
#define PITERS  50
#define LAMBDAV 0.1f

typedef __bf16 bf16x8 __attribute__((ext_vector_type(8)));
typedef float  f32x4  __attribute__((ext_vector_type(4)));

// LDS map — audited, non-overlapping, 147456 B total:
//   yF  fp32 [64][256]        @0       (65536 B)  stride 1024  (wst overlay during init)
//   wtl bf16 W-lo^T [64][256] @65536   (32768 B)  stride 512   (phase-1 B-lo)
//   whb bf16 W-hi  [256][64]  @98304   (32768 B)  stride 128   (phase-2 B-hi)
//   rhb bf16 R-hi  [64][64]   @131072  (8192 B)   stride 128
//   rlb bf16 R-lo  [64][64]   @139264  (8192 B)   stride 128
// phase-2 W-lo in registers. All hot accesses XOR-swizzled by ((row&7)<<4).
// NO unions / byte-punned aggregates anywhere: fragments are built with
// vector-element inserts + native (__bf16) casts so SROA never materializes
// a scratch alloca (R4/R5 failure mode: 174 MB/dispatch scratch FETCH).

__global__ __launch_bounds__(NTH) __attribute__((amdgpu_waves_per_eu(2, 2)))
void fista6(const float* __restrict__ inp, const float* __restrict__ Wg,
            const float* __restrict__ X0, float* __restrict__ out)
{
    __shared__ __align__(16) char lds[147456];
    __shared__ __align__(16) float vf[256];
    __shared__ __align__(16) float up[256];
    __shared__ __align__(16) float uf[64];
    __shared__ float red[16];
    __shared__ float scal[2];

    char* const yF  = lds;
    char* const wtl = lds + 65536;
    char* const whb = lds + 98304;
    char* const rhb = lds + 131072;
    char* const rlb = lds + 139264;
    char* const wst = lds;            // fp32 W staging overlay on yF

    const int tid  = threadIdx.x;
    const int w    = tid >> 6;
    const int lane = tid & 63;
    const int l4   = lane >> 4;
    const int ln   = lane & 15;
    const int rb   = blockIdx.x * 64;

    const int mi = w >> 1, nh = w & 1;   // phase-1: m-tile mi, n-tiles {2nh, 2nh+1}
    const int mp = w >> 2, nq = w & 3;   // phase-2: m-tiles {2mp,2mp+1}, n-tiles {4nq..4nq+3}

    // ---- stage W fp32 (swizzled) ----
    #pragma unroll
    for (int i = 0; i < 8; ++i) {
        int wi = (tid + i * NTH) * 4; int j = wi >> 6, k = wi & 63;
        f32x4 v = *(const f32x4*)&Wg[wi];
        *(f32x4*)(wst + j * 256 + ((k * 4) ^ ((j & 7) << 4))) = v;
    }
    // ---- bf16 planes: W-hi row-major + W-lo transposed ----
    for (int i = tid; i < 256 * 64; i += NTH) {
        int j = i >> 6, k = i & 63;
        float wv = Wg[i];
        __bf16 h = (__bf16)wv;
        __bf16 l = (__bf16)(wv - (float)h);
        *(__bf16*)(whb + j * 128 + ((k * 2) ^ ((j & 7) << 4))) = h;
        *(__bf16*)(wtl + k * 512 + ((j * 2) ^ ((k & 7) << 4))) = l;
    }

    // ---- per-thread constants ----
    float nin[2][4];
    #pragma unroll
    for (int q = 0; q < 2; ++q)
        #pragma unroll
        for (int r = 0; r < 4; ++r)
            nin[q][r] = -inp[(size_t)(rb + mi * 16 + 4 * l4 + r) * 64 + (2 * nh + q) * 16 + ln];

    float xm[2][4][4], ym[2][4][4];
    #pragma unroll
    for (int s = 0; s < 2; ++s)
      #pragma unroll
      for (int q = 0; q < 4; ++q)
        #pragma unroll
        for (int r = 0; r < 4; ++r) {
            float v = X0[(size_t)(rb + (2 * mp + s) * 16 + 4 * l4 + r) * 256 + (4 * nq + q) * 16 + ln];
            xm[s][q][r] = v; ym[s][q][r] = v;
        }

    if (tid < 256) vf[tid] = 0.0625f;
    __syncthreads();

    // ---- Lipschitz: 50 power iterations of Q = 2 W W^T (R2-verified) ----
    for (int it = 0; it <= PITERS; ++it) {
        if (tid < 256) {
            int col = tid & 63, jq = tid >> 6;
            float s = 0.f;
            #pragma unroll 4
            for (int j = jq * 64; j < jq * 64 + 64; ++j)
                s += vf[j] * *(const float*)(wst + j * 256 + ((col * 4) ^ ((j & 7) << 4)));
            up[tid] = s;
        }
        __syncthreads();
        if (tid < 64) uf[tid] = up[tid] + up[tid + 64] + up[tid + 128] + up[tid + 192];
        __syncthreads();
        float w2 = 0.f;
        if (tid < 256) {
            float s = 0.f;
            #pragma unroll
            for (int kc = 0; kc < 64; kc += 4) {
                f32x4 wv = *(const f32x4*)(wst + tid * 256 + ((kc * 4) ^ ((tid & 7) << 4)));
                f32x4 u4 = *(const f32x4*)&uf[kc];
                s += wv.x * u4.x + wv.y * u4.y + wv.z * u4.z + wv.w * u4.w;
            }
            w2 = 2.f * s;
        }
        float sq = (tid < 256) ? ((it == PITERS) ? vf[tid] * w2 : w2 * w2) : 0.f;
        #pragma unroll
        for (int off = 32; off >= 1; off >>= 1) sq += __shfl_down(sq, off);
        if (tid < 256 && lane == 0) red[tid >> 6] = sq;
        __syncthreads();
        float tot = red[0] + red[1] + red[2] + red[3];
        if (it < PITERS) { if (tid < 256) vf[tid] = w2 * (1.f / sqrtf(tot)); }
        else if (tid == 0) { scal[0] = 1.f / tot; scal[1] = LAMBDAV / tot; }
        __syncthreads();
    }
    const float c2  = 2.f * scal[0];
    const float thr = scal[1];

    // ---- phase-1 W-hi fragments -> registers (16 frags = 64 VGPR) ----
    bf16x8 wbh[2][8];
    #pragma unroll
    for (int q = 0; q < 2; ++q) {
        const int col4 = ((2 * nh + q) * 16 + ln) * 4;
        #pragma unroll
        for (int c = 0; c < 8; ++c) {
            bf16x8 p{};
            #pragma unroll
            for (int t = 0; t < 8; ++t) {
                int j = c * 32 + 8 * l4 + t;
                p[t] = (__bf16)(*(const float*)(wst + j * 256 + (col4 ^ ((j & 7) << 4))));
            }
            wbh[q][c] = p;
        }
    }
    // ---- phase-2 W-lo fragments -> registers (8 frags = 32 VGPR) ----
    bf16x8 w2lo[4][2];
    #pragma unroll
    for (int q = 0; q < 4; ++q) {
        const int brow = (4 * nq + q) * 16 + ln;
        #pragma unroll
        for (int c = 0; c < 2; ++c) {
            bf16x8 p{};
            #pragma unroll
            for (int t = 0; t < 8; ++t) {
                int k = c * 32 + 8 * l4 + t;
                float wv = *(const float*)(wst + brow * 256 + ((k * 4) ^ ((brow & 7) << 4)));
                __bf16 h = (__bf16)wv;
                p[t] = (__bf16)(wv - (float)h);
            }
            w2lo[q][c] = p;
        }
    }
    __syncthreads();   // all wst consumers done; yF region free

    // ---- y0 = X0 into fp32 LDS ----
    #pragma unroll
    for (int s = 0; s < 2; ++s)
      #pragma unroll
      for (int q = 0; q < 4; ++q)
        #pragma unroll
        for (int r = 0; r < 4; ++r) {
            int row = (2 * mp + s) * 16 + 4 * l4 + r;
            int col = (4 * nq + q) * 16 + ln;
            *(float*)(yF + row * 1024 + ((col * 4) ^ ((row & 7) << 4))) = ym[s][q][r];
        }
    __syncthreads();

    const int arow = mi * 16 + ln;
    const int ax   = (arow & 7) << 4;
    const int b0   = (2 * nh) * 16 + ln;
    const int b1   = b0 + 16;
    const int bx   = (ln & 7) << 4;           // b0&7 == b1&7 == ln&7

    float tt = 1.f;
    for (int step = 0; step < NSTEPS; ++step) {
        // ======== phase 1: R = y W - in ========
        f32x4 a0 = { nin[0][0], nin[0][1], nin[0][2], nin[0][3] };
        f32x4 a1 = { nin[1][0], nin[1][1], nin[1][2], nin[1][3] };
        #pragma unroll
        for (int c = 0; c < 8; ++c) {
            const int lb = c * 128 + l4 * 32;
            f32x4 v0 = *(const f32x4*)(yF + arow * 1024 + (lb ^ ax));
            f32x4 v1 = *(const f32x4*)(yF + arow * 1024 + ((lb + 16) ^ ax));
            bf16x8 ah{}, al{};
            #pragma unroll
            for (int t = 0; t < 4; ++t) {
                float f = v0[t];
                __bf16 h = (__bf16)f;
                ah[t] = h;
                al[t] = (__bf16)(f - (float)h);
            }
            #pragma unroll
            for (int t = 0; t < 4; ++t) {
                float f = v1[t];
                __bf16 h = (__bf16)f;
                ah[4 + t] = h;
                al[4 + t] = (__bf16)(f - (float)h);
            }
            const int kb = c * 64 + l4 * 16;
            bf16x8 bl0 = *(const bf16x8*)(wtl + b0 * 512 + (kb ^ bx));
            bf16x8 bl1 = *(const bf16x8*)(wtl + b1 * 512 + (kb ^ bx));
            a0 = __builtin_amdgcn_mfma_f32_16x16x32_bf16(ah, wbh[0][c], a0, 0, 0, 0);
            a0 = __builtin_amdgcn_mfma_f32_16x16x32_bf16(al, wbh[0][c], a0, 0, 0, 0);
            a0 = __builtin_amdgcn_mfma_f32_16x16x32_bf16(ah, bl0,       a0, 0, 0, 0);
            a1 = __builtin_amdgcn_mfma_f32_16x16x32_bf16(ah, wbh[1][c], a1, 0, 0, 0);
            a1 = __builtin_amdgcn_mfma_f32_16x16x32_bf16(al, wbh[1][c], a1, 0, 0, 0);
            a1 = __builtin_amdgcn_mfma_f32_16x16x32_bf16(ah, bl1,       a1, 0, 0, 0);
        }
        #pragma unroll
        for (int q = 0; q < 2; ++q)
            #pragma unroll
            for (int r = 0; r < 4; ++r) {
                int row = mi * 16 + 4 * l4 + r;
                int off = row * 128 + ((((2 * nh + q) * 16 + ln) * 2) ^ ((row & 7) << 4));
                float v = q ? a1[r] : a0[r];
                __bf16 h = (__bf16)v;
                *(__bf16*)(rhb + off) = h;
                *(__bf16*)(rlb + off) = (__bf16)(v - (float)h);
            }
        __syncthreads();

        // ======== phase 2: g = R W^T ========
        f32x4 g2[2][4];
        #pragma unroll
        for (int s = 0; s < 2; ++s)
            #pragma unroll
            for (int q = 0; q < 4; ++q) g2[s][q] = (f32x4){0.f, 0.f, 0.f, 0.f};
        #pragma unroll
        for (int c = 0; c < 2; ++c) {
            const int kb = c * 64 + l4 * 16;
            const int r0 = (2 * mp) * 16 + ln;
            const int r1 = r0 + 16;
            const int rx = (ln & 7) << 4;
            bf16x8 rh0 = *(const bf16x8*)(rhb + r0 * 128 + (kb ^ rx));
            bf16x8 rl0 = *(const bf16x8*)(rlb + r0 * 128 + (kb ^ rx));
            bf16x8 rh1 = *(const bf16x8*)(rhb + r1 * 128 + (kb ^ rx));
            bf16x8 rl1 = *(const bf16x8*)(rlb + r1 * 128 + (kb ^ rx));
            #pragma unroll
            for (int q = 0; q < 4; ++q) {
                const int brow = (4 * nq + q) * 16 + ln;
                bf16x8 bh = *(const bf16x8*)(whb + brow * 128 + (kb ^ rx));
                g2[0][q] = __builtin_amdgcn_mfma_f32_16x16x32_bf16(rh0, bh,         g2[0][q], 0, 0, 0);
                g2[0][q] = __builtin_amdgcn_mfma_f32_16x16x32_bf16(rl0, bh,         g2[0][q], 0, 0, 0);
                g2[0][q] = __builtin_amdgcn_mfma_f32_16x16x32_bf16(rh0, w2lo[q][c], g2[0][q], 0, 0, 0);
                g2[1][q] = __builtin_amdgcn_mfma_f32_16x16x32_bf16(rh1, bh,         g2[1][q], 0, 0, 0);
                g2[1][q] = __builtin_amdgcn_mfma_f32_16x16x32_bf16(rl1, bh,         g2[1][q], 0, 0, 0);
                g2[1][q] = __builtin_amdgcn_mfma_f32_16x16x32_bf16(rh1, w2lo[q][c], g2[1][q], 0, 0, 0);
            }
        }

        // ======== update: prox + momentum, write y (fp32) ========
        const float t2v = 0.5f + 0.5f * sqrtf(1.f + 4.f * tt * tt);
        const float mom = (tt - 1.f) / t2v;
        tt = t2v;
        #pragma unroll
        for (int s = 0; s < 2; ++s)
          #pragma unroll
          for (int q = 0; q < 4; ++q)
            #pragma unroll
            for (int r = 0; r < 4; ++r) {
                float u  = ym[s][q][r] - c2 * g2[s][q][r];
                float x2 = fmaxf(u - thr, 0.f) + fminf(u + thr, 0.f);
                float yn = x2 + mom * (x2 - xm[s][q][r]);
                xm[s][q][r] = x2; ym[s][q][r] = yn;
                int row = (2 * mp + s) * 16 + 4 * l4 + r;
                int col = (4 * nq + q) * 16 + ln;
                *(float*)(yF + row * 1024 + ((col * 4) ^ ((row & 7) << 4))) = yn;
            }
        __syncthreads();
    }

    // ---- store X ----
    #pragma unroll
    for (int s = 0; s < 2; ++s)
      #pragma unroll
      for (int q = 0; q < 4; ++q)
        #pragma unroll
        for (int r = 0; r < 4; ++r)
            out[(size_t)(rb + (2 * mp + s) * 16 + 4 * l4 + r) * 256 + (4 * nq + q) * 16 + ln] = xm[s][q][r];
}

extern "C" void kernel_launch(void* const* d_in, const int* in_sizes, int n_in,
                              void* d_out, int out_size, void* d_ws, size_t ws_size,
                              hipStream_t stream) {
    (void)in_sizes; (void)n_in; (void)d_ws; (void)ws_size; (void)out_size;
    const float* inp = (const float*)d_in[0];   // [16384, 64]
    const float* Wg  = (const float*)d_in[1];   // [256, 64]
    const float* X0  = (const float*)d_in[2];   // [16384, 256]
    float* outp      = (float*)d_out;           // [16384, 256]
    fista6<<<16384 / 64, NTH, 0, stream>>>(inp, Wg, X0, outp);
}

// Round 7
// 649.115 us; speedup vs baseline: 1.7334x; 1.6437x over previous
//
#include <hip/hip_runtime.h>
#include <hip/hip_bf16.h>

#define NTH     512
#define NSTEPS  100
#define PITERS  50
#define LAMBDAV 0.1f

typedef __bf16 bf16x8 __attribute__((ext_vector_type(8)));
typedef float  f32x4  __attribute__((ext_vector_type(4)));

// LDS map — audited, non-overlapping, 147456 B total:
//   yF  fp32 [64][256]        @0       (65536 B)  stride 1024  (wst overlay during init)
//   wtl bf16 W-lo^T [64][256] @65536   (32768 B)  stride 512   (phase-1 B-lo)
//   whb bf16 W-hi  [256][64]  @98304   (32768 B)  stride 128   (phase-2 B-hi)
//   rhb bf16 R-hi  [64][64]   @131072  (8192 B)   stride 128
//   rlb bf16 R-lo  [64][64]   @139264  (8192 B)   stride 128
// Register budget discipline (R4-R6 lesson): persistent per-thread state must
// stay <= ~136 (R2-proven): wbh 64 + w2lo 32 + xm 32 + nin 8 = 136.
// y lives ONLY in LDS; update reads it back (own cells only — race-free).

__global__ __launch_bounds__(NTH) __attribute__((amdgpu_waves_per_eu(2, 2)))
void fista7(const float* __restrict__ inp, const float* __restrict__ Wg,
            const float* __restrict__ X0, float* __restrict__ out)
{
    __shared__ __align__(16) char lds[147456];
    __shared__ __align__(16) float vf[256];
    __shared__ __align__(16) float up[256];
    __shared__ __align__(16) float uf[64];
    __shared__ float red[16];
    __shared__ float scal[2];

    char* const yF  = lds;
    char* const wtl = lds + 65536;
    char* const whb = lds + 98304;
    char* const rhb = lds + 131072;
    char* const rlb = lds + 139264;
    char* const wst = lds;            // fp32 W staging overlay on yF

    const int tid  = threadIdx.x;
    const int w    = tid >> 6;
    const int lane = tid & 63;
    const int l4   = lane >> 4;
    const int ln   = lane & 15;
    const int rb   = blockIdx.x * 64;

    const int mi = w >> 1, nh = w & 1;   // phase-1: m-tile mi, n-tiles {2nh, 2nh+1}
    const int mp = w >> 2, nq = w & 3;   // phase-2: m-tiles {2mp,2mp+1}, n-tiles {4nq..4nq+3}

    // ---- stage W fp32 (swizzled) ----
    #pragma unroll
    for (int i = 0; i < 8; ++i) {
        int wi = (tid + i * NTH) * 4; int j = wi >> 6, k = wi & 63;
        f32x4 v = *(const f32x4*)&Wg[wi];
        *(f32x4*)(wst + j * 256 + ((k * 4) ^ ((j & 7) << 4))) = v;
    }
    // ---- bf16 planes: W-hi row-major + W-lo transposed ----
    for (int i = tid; i < 256 * 64; i += NTH) {
        int j = i >> 6, k = i & 63;
        float wv = Wg[i];
        __bf16 h = (__bf16)wv;
        __bf16 l = (__bf16)(wv - (float)h);
        *(__bf16*)(whb + j * 128 + ((k * 2) ^ ((j & 7) << 4))) = h;
        *(__bf16*)(wtl + k * 512 + ((j * 2) ^ ((k & 7) << 4))) = l;
    }

    // ---- per-thread constants ----
    float nin[2][4];
    #pragma unroll
    for (int q = 0; q < 2; ++q)
        #pragma unroll
        for (int r = 0; r < 4; ++r)
            nin[q][r] = -inp[(size_t)(rb + mi * 16 + 4 * l4 + r) * 64 + (2 * nh + q) * 16 + ln];

    float xm[2][4][4];
    #pragma unroll
    for (int s = 0; s < 2; ++s)
      #pragma unroll
      for (int q = 0; q < 4; ++q)
        #pragma unroll
        for (int r = 0; r < 4; ++r)
            xm[s][q][r] = X0[(size_t)(rb + (2 * mp + s) * 16 + 4 * l4 + r) * 256 + (4 * nq + q) * 16 + ln];

    if (tid < 256) vf[tid] = 0.0625f;
    __syncthreads();

    // ---- Lipschitz: 50 power iterations of Q = 2 W W^T (R2-verified) ----
    for (int it = 0; it <= PITERS; ++it) {
        if (tid < 256) {
            int col = tid & 63, jq = tid >> 6;
            float s = 0.f;
            #pragma unroll 4
            for (int j = jq * 64; j < jq * 64 + 64; ++j)
                s += vf[j] * *(const float*)(wst + j * 256 + ((col * 4) ^ ((j & 7) << 4)));
            up[tid] = s;
        }
        __syncthreads();
        if (tid < 64) uf[tid] = up[tid] + up[tid + 64] + up[tid + 128] + up[tid + 192];
        __syncthreads();
        float w2 = 0.f;
        if (tid < 256) {
            float s = 0.f;
            #pragma unroll
            for (int kc = 0; kc < 64; kc += 4) {
                f32x4 wv = *(const f32x4*)(wst + tid * 256 + ((kc * 4) ^ ((tid & 7) << 4)));
                f32x4 u4 = *(const f32x4*)&uf[kc];
                s += wv.x * u4.x + wv.y * u4.y + wv.z * u4.z + wv.w * u4.w;
            }
            w2 = 2.f * s;
        }
        float sq = (tid < 256) ? ((it == PITERS) ? vf[tid] * w2 : w2 * w2) : 0.f;
        #pragma unroll
        for (int off = 32; off >= 1; off >>= 1) sq += __shfl_down(sq, off);
        if (tid < 256 && lane == 0) red[tid >> 6] = sq;
        __syncthreads();
        float tot = red[0] + red[1] + red[2] + red[3];
        if (it < PITERS) { if (tid < 256) vf[tid] = w2 * (1.f / sqrtf(tot)); }
        else if (tid == 0) { scal[0] = 1.f / tot; scal[1] = LAMBDAV / tot; }
        __syncthreads();
    }
    const float c2  = 2.f * scal[0];
    const float thr = scal[1];

    // ---- phase-1 W-hi fragments -> registers (16 frags = 64 VGPR) ----
    bf16x8 wbh[2][8];
    #pragma unroll
    for (int q = 0; q < 2; ++q) {
        const int col4 = ((2 * nh + q) * 16 + ln) * 4;
        #pragma unroll
        for (int c = 0; c < 8; ++c) {
            bf16x8 p{};
            #pragma unroll
            for (int t = 0; t < 8; ++t) {
                int j = c * 32 + 8 * l4 + t;
                p[t] = (__bf16)(*(const float*)(wst + j * 256 + (col4 ^ ((j & 7) << 4))));
            }
            wbh[q][c] = p;
        }
    }
    // ---- phase-2 W-lo fragments -> registers (8 frags = 32 VGPR) ----
    bf16x8 w2lo[4][2];
    #pragma unroll
    for (int q = 0; q < 4; ++q) {
        const int brow = (4 * nq + q) * 16 + ln;
        #pragma unroll
        for (int c = 0; c < 2; ++c) {
            bf16x8 p{};
            #pragma unroll
            for (int t = 0; t < 8; ++t) {
                int k = c * 32 + 8 * l4 + t;
                float wv = *(const float*)(wst + brow * 256 + ((k * 4) ^ ((brow & 7) << 4)));
                __bf16 h = (__bf16)wv;
                p[t] = (__bf16)(wv - (float)h);
            }
            w2lo[q][c] = p;
        }
    }
    __syncthreads();   // all wst consumers done; yF region free

    // ---- y0 = X0 into fp32 LDS ----
    #pragma unroll
    for (int s = 0; s < 2; ++s)
      #pragma unroll
      for (int q = 0; q < 4; ++q)
        #pragma unroll
        for (int r = 0; r < 4; ++r) {
            int row = (2 * mp + s) * 16 + 4 * l4 + r;
            int col = (4 * nq + q) * 16 + ln;
            *(float*)(yF + row * 1024 + ((col * 4) ^ ((row & 7) << 4))) = xm[s][q][r];
        }
    __syncthreads();

    const int arow = mi * 16 + ln;
    const int ax   = (arow & 7) << 4;
    const int b0   = (2 * nh) * 16 + ln;
    const int b1   = b0 + 16;
    const int bx   = (ln & 7) << 4;           // b0&7 == b1&7 == ln&7

    float tt = 1.f;
    for (int step = 0; step < NSTEPS; ++step) {
        // ======== phase 1: R = y W - in ========
        f32x4 a0 = { nin[0][0], nin[0][1], nin[0][2], nin[0][3] };
        f32x4 a1 = { nin[1][0], nin[1][1], nin[1][2], nin[1][3] };
        #pragma unroll
        for (int c = 0; c < 8; ++c) {
            const int lb = c * 128 + l4 * 32;
            f32x4 v0 = *(const f32x4*)(yF + arow * 1024 + (lb ^ ax));
            f32x4 v1 = *(const f32x4*)(yF + arow * 1024 + ((lb + 16) ^ ax));
            bf16x8 ah{}, al{};
            #pragma unroll
            for (int t = 0; t < 4; ++t) {
                float f = v0[t];
                __bf16 h = (__bf16)f;
                ah[t] = h;
                al[t] = (__bf16)(f - (float)h);
            }
            #pragma unroll
            for (int t = 0; t < 4; ++t) {
                float f = v1[t];
                __bf16 h = (__bf16)f;
                ah[4 + t] = h;
                al[4 + t] = (__bf16)(f - (float)h);
            }
            const int kb = c * 64 + l4 * 16;
            bf16x8 bl0 = *(const bf16x8*)(wtl + b0 * 512 + (kb ^ bx));
            bf16x8 bl1 = *(const bf16x8*)(wtl + b1 * 512 + (kb ^ bx));
            a0 = __builtin_amdgcn_mfma_f32_16x16x32_bf16(ah, wbh[0][c], a0, 0, 0, 0);
            a0 = __builtin_amdgcn_mfma_f32_16x16x32_bf16(al, wbh[0][c], a0, 0, 0, 0);
            a0 = __builtin_amdgcn_mfma_f32_16x16x32_bf16(ah, bl0,       a0, 0, 0, 0);
            a1 = __builtin_amdgcn_mfma_f32_16x16x32_bf16(ah, wbh[1][c], a1, 0, 0, 0);
            a1 = __builtin_amdgcn_mfma_f32_16x16x32_bf16(al, wbh[1][c], a1, 0, 0, 0);
            a1 = __builtin_amdgcn_mfma_f32_16x16x32_bf16(ah, bl1,       a1, 0, 0, 0);
        }
        #pragma unroll
        for (int q = 0; q < 2; ++q)
            #pragma unroll
            for (int r = 0; r < 4; ++r) {
                int row = mi * 16 + 4 * l4 + r;
                int off = row * 128 + ((((2 * nh + q) * 16 + ln) * 2) ^ ((row & 7) << 4));
                float v = q ? a1[r] : a0[r];
                __bf16 h = (__bf16)v;
                *(__bf16*)(rhb + off) = h;
                *(__bf16*)(rlb + off) = (__bf16)(v - (float)h);
            }
        __syncthreads();

        // ======== phase 2: g = R W^T ========
        f32x4 g2[2][4];
        #pragma unroll
        for (int s = 0; s < 2; ++s)
            #pragma unroll
            for (int q = 0; q < 4; ++q) g2[s][q] = (f32x4){0.f, 0.f, 0.f, 0.f};
        #pragma unroll
        for (int c = 0; c < 2; ++c) {
            const int kb = c * 64 + l4 * 16;
            const int r0 = (2 * mp) * 16 + ln;
            const int r1 = r0 + 16;
            const int rx = (ln & 7) << 4;
            bf16x8 rh0 = *(const bf16x8*)(rhb + r0 * 128 + (kb ^ rx));
            bf16x8 rl0 = *(const bf16x8*)(rlb + r0 * 128 + (kb ^ rx));
            bf16x8 rh1 = *(const bf16x8*)(rhb + r1 * 128 + (kb ^ rx));
            bf16x8 rl1 = *(const bf16x8*)(rlb + r1 * 128 + (kb ^ rx));
            #pragma unroll
            for (int q = 0; q < 4; ++q) {
                const int brow = (4 * nq + q) * 16 + ln;
                bf16x8 bh = *(const bf16x8*)(whb + brow * 128 + (kb ^ rx));
                g2[0][q] = __builtin_amdgcn_mfma_f32_16x16x32_bf16(rh0, bh,         g2[0][q], 0, 0, 0);
                g2[0][q] = __builtin_amdgcn_mfma_f32_16x16x32_bf16(rl0, bh,         g2[0][q], 0, 0, 0);
                g2[0][q] = __builtin_amdgcn_mfma_f32_16x16x32_bf16(rh0, w2lo[q][c], g2[0][q], 0, 0, 0);
                g2[1][q] = __builtin_amdgcn_mfma_f32_16x16x32_bf16(rh1, bh,         g2[1][q], 0, 0, 0);
                g2[1][q] = __builtin_amdgcn_mfma_f32_16x16x32_bf16(rl1, bh,         g2[1][q], 0, 0, 0);
                g2[1][q] = __builtin_amdgcn_mfma_f32_16x16x32_bf16(rh1, w2lo[q][c], g2[1][q], 0, 0, 0);
            }
        }

        // ======== update: prox + momentum; y read from + written to LDS ========
        const float t2v = 0.5f + 0.5f * sqrtf(1.f + 4.f * tt * tt);
        const float mom = (tt - 1.f) / t2v;
        tt = t2v;
        #pragma unroll
        for (int s = 0; s < 2; ++s)
          #pragma unroll
          for (int q = 0; q < 4; ++q)
            #pragma unroll
            for (int r = 0; r < 4; ++r) {
                int row = (2 * mp + s) * 16 + 4 * l4 + r;
                int col = (4 * nq + q) * 16 + ln;
                float* yp = (float*)(yF + row * 1024 + ((col * 4) ^ ((row & 7) << 4)));
                float yv = *yp;                      // own cell — race-free
                float u  = yv - c2 * g2[s][q][r];
                float x2 = fmaxf(u - thr, 0.f) + fminf(u + thr, 0.f);
                float yn = x2 + mom * (x2 - xm[s][q][r]);
                xm[s][q][r] = x2;
                *yp = yn;
            }
        __syncthreads();
    }

    // ---- store X ----
    #pragma unroll
    for (int s = 0; s < 2; ++s)
      #pragma unroll
      for (int q = 0; q < 4; ++q)
        #pragma unroll
        for (int r = 0; r < 4; ++r)
            out[(size_t)(rb + (2 * mp + s) * 16 + 4 * l4 + r) * 256 + (4 * nq + q) * 16 + ln] = xm[s][q][r];
}

extern "C" void kernel_launch(void* const* d_in, const int* in_sizes, int n_in,
                              void* d_out, int out_size, void* d_ws, size_t ws_size,
                              hipStream_t stream) {
    (void)in_sizes; (void)n_in; (void)d_ws; (void)ws_size; (void)out_size;
    const float* inp = (const float*)d_in[0];   // [16384, 64]
    const float* Wg  = (const float*)d_in[1];   // [256, 64]
    const float* X0  = (const float*)d_in[2];   // [16384, 256]
    float* outp      = (float*)d_out;           // [16384, 256]
    fista7<<<16384 / 64, NTH, 0, stream>>>(inp, Wg, X0, outp);
}